// Round 2
// baseline (800.616 us; speedup 1.0000x reference)
//
#include <hip/hip_runtime.h>
#include <hip/hip_bf16.h>

#define B_ 32
#define T_ 12
#define N_ 300
#define D_ 128
#define M_ 288

// ws layout (floats): kT[128][288] | v[288][128] | wqT[128][128]
#define WS_KT   0
#define WS_V    (D_*M_)            // 36864
#define WS_WQT  (D_*M_ + M_*D_)    // 73728

// ---------------------------------------------------------------------------
// prep: k^T, v (fp32) from memory @ {wk,wv}^T + bias; wq transposed.
// blocks 0..287: one memory row m.  blocks 288..415: one wq column e.
// ---------------------------------------------------------------------------
__global__ __launch_bounds__(D_) void prep_kernel(
    const float* __restrict__ memory,
    const float* __restrict__ wk, const float* __restrict__ bk,
    const float* __restrict__ wv, const float* __restrict__ bv,
    const float* __restrict__ wq,
    float* __restrict__ ws) {
  float* kT  = ws + WS_KT;
  float* v   = ws + WS_V;
  float* wqT = ws + WS_WQT;
  const int blk = blockIdx.x;
  const int d   = threadIdx.x;
  if (blk < M_) {
    const int m = blk;
    float ka = 0.f, va = 0.f;
    for (int e = 0; e < D_; ++e) {
      const float me = memory[m*D_ + e];
      ka += me * wk[d*D_ + e];
      va += me * wv[d*D_ + e];
    }
    ka += bk[d];
    va += bv[d];
    kT[d*M_ + m] = ka;     // transposed: coalesced reads in score phase
    v[m*D_ + d]  = va;     // row-major: coalesced reads in out phase
  } else {
    const int e = blk - M_;
    wqT[e*D_ + d] = wq[d*D_ + e];
  }
}

// ---------------------------------------------------------------------------
// main: one block per (b,n). 256 threads (4 waves).
// ---------------------------------------------------------------------------
__global__ __launch_bounds__(256) void attn_kernel(
    const float* __restrict__ x,
    const float* __restrict__ memory,
    const float* __restrict__ bq,
    const float* __restrict__ ws,
    float* __restrict__ out) {
  const float* kT  = ws + WS_KT;
  const float* v   = ws + WS_V;
  const float* wqT = ws + WS_WQT;

  __shared__ __align__(16) float qs[T_*D_];   // 6144 B  : q rows
  __shared__ __align__(16) float ss[T_*M_];   // 13824 B : scores -> exp(p); overlays xs
  __shared__ float rowinv[T_];
  __shared__ int   top2i[T_*2];
  float* xs = ss;                  // x rows live here during phases 1-2

  const int tid = threadIdx.x;
  const int bid = blockIdx.x;
  const int b = bid / N_;
  const int n = bid % N_;

  // ---- phase 1: load x[b, :, n, :] -> LDS (float4) -----------------------
  for (int i = tid; i < T_*(D_/4); i += 256) {      // 384 float4s
    const int t = i >> 5, d4 = i & 31;
    ((float4*)xs)[i] =
        ((const float4*)x)[(((size_t)b*T_ + t)*N_ + n)*(D_/4) + d4];
  }
  __syncthreads();

  // ---- phase 2: q = x @ wq^T + bq  (thread: fixed d, 6 t's) --------------
  {
    const int d = tid & 127, h = tid >> 7;
    float acc[6] = {0.f,0.f,0.f,0.f,0.f,0.f};
    for (int e4 = 0; e4 < D_/4; ++e4) {
      const int e = e4*4;
      const float w0 = wqT[(e+0)*D_ + d];
      const float w1 = wqT[(e+1)*D_ + d];
      const float w2 = wqT[(e+2)*D_ + d];
      const float w3 = wqT[(e+3)*D_ + d];
#pragma unroll
      for (int j = 0; j < 6; ++j) {
        const float4 xv = *(const float4*)&xs[(h*6+j)*D_ + e];
        acc[j] += xv.x*w0; acc[j] += xv.y*w1; acc[j] += xv.z*w2; acc[j] += xv.w*w3;
      }
    }
    const float bqd = bq[d];
#pragma unroll
    for (int j = 0; j < 6; ++j) qs[(h*6+j)*D_ + d] = acc[j] + bqd;
  }
  __syncthreads();   // qs ready; xs dead -> ss region reusable

  // ---- phase 3: scores s[t][m] = q[t].k[m] / sqrt(D)  (thread: column m) -
  {
    for (int pass = 0; pass < 2; ++pass) {
      const int m = tid + pass*256;
      if (m < M_) {
        float acc[T_];
#pragma unroll
        for (int t = 0; t < T_; ++t) acc[t] = 0.f;
        for (int e4 = 0; e4 < D_/4; ++e4) {
          const int e = e4*4;
          const float k0 = kT[(e+0)*M_ + m];
          const float k1 = kT[(e+1)*M_ + m];
          const float k2 = kT[(e+2)*M_ + m];
          const float k3 = kT[(e+3)*M_ + m];
#pragma unroll
          for (int t = 0; t < T_; ++t) {
            const float4 qv = *(const float4*)&qs[t*D_ + e];
            acc[t] += qv.x*k0; acc[t] += qv.y*k1; acc[t] += qv.z*k2; acc[t] += qv.w*k3;
          }
        }
#pragma unroll
        for (int t = 0; t < T_; ++t)
          ss[t*M_ + m] = acc[t] * 0.08838834764831845f;  // 1/sqrt(128)
      }
    }
  }
  __syncthreads();

  // ---- phase 4: per-row softmax prep + exact top-2 (wave per row) --------
  {
    const int wave = tid >> 6, lane = tid & 63;
    for (int r = wave; r < T_; r += 4) {
      float v1 = -__builtin_inff(), v2 = -__builtin_inff();
      int i1 = 0, i2 = 0;
      for (int m = lane; m < M_; m += 64) {
        const float s = ss[r*M_ + m];
        if (s > v1)      { v2 = v1; i2 = i1; v1 = s; i1 = m; }
        else if (s > v2) { v2 = s; i2 = m; }
      }
#pragma unroll
      for (int off = 32; off > 0; off >>= 1) {
        const float o1 = __shfl_xor(v1, off, 64);
        const int  oi1 = __shfl_xor(i1, off, 64);
        const float o2 = __shfl_xor(v2, off, 64);
        const int  oi2 = __shfl_xor(i2, off, 64);
        const bool b_first = (o1 > v1) || (o1 == v1 && oi1 < i1);
        if (b_first) {
          const bool a_second = (v1 > o2) || (v1 == o2 && i1 < oi2);
          v2 = a_second ? v1 : o2;  i2 = a_second ? i1 : oi2;
          v1 = o1; i1 = oi1;
        } else {
          const bool b_second = (o1 > v2) || (o1 == v2 && oi1 < i2);
          if (b_second) { v2 = o1; i2 = oi1; }
        }
      }
      const float rowmax = v1;
      float psum = 0.f;
      for (int m = lane; m < M_; m += 64) {
        const float e = expf(ss[r*M_ + m] - rowmax);
        ss[r*M_ + m] = e;
        psum += e;
      }
#pragma unroll
      for (int off = 32; off > 0; off >>= 1) psum += __shfl_xor(psum, off, 64);
      if (lane == 0) {
        rowinv[r]     = 1.0f / psum;
        top2i[r*2]    = i1;
        top2i[r*2+1]  = i2;
      }
    }
  }
  __syncthreads();

  // ---- phase 5: out = (P @ v) * rowinv ; write fp32 ----------------------
  {
    const int d = tid & 127, h = tid >> 7;
    float acc[6] = {0.f,0.f,0.f,0.f,0.f,0.f};
    for (int m4 = 0; m4 < M_/4; ++m4) {
      const int m = m4*4;
      const float v0  = v[(m+0)*D_ + d];
      const float v1_ = v[(m+1)*D_ + d];
      const float v2_ = v[(m+2)*D_ + d];
      const float v3_ = v[(m+3)*D_ + d];
#pragma unroll
      for (int j = 0; j < 6; ++j) {
        const float4 pv = *(const float4*)&ss[(h*6+j)*M_ + m];
        acc[j] += pv.x*v0; acc[j] += pv.y*v1_; acc[j] += pv.z*v2_; acc[j] += pv.w*v3_;
      }
    }
#pragma unroll
    for (int j = 0; j < 6; ++j) {
      const int t = h*6 + j;
      out[(((size_t)b*T_ + t)*N_ + n)*D_ + d] = acc[j] * rowinv[t];
    }
  }

  // ---- phase 6: pos/neg gathers (float4 passthrough, exact) --------------
  {
    const size_t sec4 = (size_t)B_*T_*N_*(D_/4);
    for (int i = tid; i < 2*T_*(D_/4); i += 256) {   // 768 float4s
      const int sel = i / (T_*(D_/4));
      const int r   = (i >> 5) % T_;
      const int d4  = i & 31;
      const int idx = top2i[r*2 + sel];
      ((float4*)out)[(2+sel)*sec4 + (((size_t)b*T_ + r)*N_ + n)*(D_/4) + d4] =
          ((const float4*)memory)[idx*(D_/4) + d4];
    }
  }
}

// ---------------------------------------------------------------------------
extern "C" void kernel_launch(void* const* d_in, const int* in_sizes, int n_in,
                              void* d_out, int out_size, void* d_ws, size_t ws_size,
                              hipStream_t stream) {
  const float* x      = (const float*)d_in[0];
  const float* memory = (const float*)d_in[1];
  const float* wq     = (const float*)d_in[2];
  const float* bq     = (const float*)d_in[3];
  const float* wk     = (const float*)d_in[4];
  const float* bk     = (const float*)d_in[5];
  const float* wv     = (const float*)d_in[6];
  const float* bv     = (const float*)d_in[7];
  float* out = (float*)d_out;
  float* ws  = (float*)d_ws;

  const size_t sec = (size_t)B_*T_*N_*D_;
  // output section 1 is a verbatim copy of x
  hipMemcpyAsync(out + sec, x, sec * sizeof(float),
                 hipMemcpyDeviceToDevice, stream);

  prep_kernel<<<dim3(M_ + D_), dim3(D_), 0, stream>>>(memory, wk, bk, wv, bv, wq, ws);
  attn_kernel<<<dim3(B_*N_), dim3(256), 0, stream>>>(x, memory, bq, ws, out);
}